// Round 8
// baseline (467.625 us; speedup 1.0000x reference)
//
#include <hip/hip_runtime.h>
#include <math.h>

// ---------------------------------------------------------------------------
// Mamba forward. Round 8:
//  - BK=64 GEMM K-loop (half the barrier drains, 2x MFMA per drain)
//  - embed GEMM folded into layer-1 in_proj: Wc1 = ipw[0] @ in_w (precomputed
//    in prep), so L1 in_proj is K=32; bias1 = ipw[0] @ in_b
//  - scan_mid fused into scan_passA (last-block-arrival, device atomics)
//  - launches 17 -> 14
// Shapes: B=8 L=1024 ENC=32 DM=256 DI=512 DS=16 DC=4 DTR=16 LAYERS=2 DFF=1024
// ---------------------------------------------------------------------------

static constexpr int L_SEQ = 1024;
static constexpr int M_ROWS = 8 * 1024;   // B*L
static constexpr int NCHUNK = 32;
static constexpr int TCHUNK = 32;         // L_SEQ / NCHUNK

typedef unsigned short u16;
typedef unsigned short u16x8 __attribute__((ext_vector_type(8)));
typedef unsigned short u16x4 __attribute__((ext_vector_type(4)));
typedef short bf16x8 __attribute__((ext_vector_type(8)));   // MFMA operand type
typedef float f32x4 __attribute__((ext_vector_type(4)));

__device__ __forceinline__ float silu_f(float x) { return x / (1.f + __expf(-x)); }
__device__ __forceinline__ float softplus_f(float x) {
  return (x > 20.f) ? x : log1pf(__expf(x));
}
__device__ __forceinline__ u16 f2bf(float f) {          // RNE fp32->bf16
  unsigned u = __builtin_bit_cast(unsigned, f);
  u += 0x7FFFu + ((u >> 16) & 1u);
  return (u16)(u >> 16);
}
__device__ __forceinline__ float bf2f(u16 v) {
  return __builtin_bit_cast(float, (unsigned)v << 16);
}

// async global->LDS, 16 B per lane; LDS dest = uniform base + lane*16
__device__ __forceinline__ void gll16(const u16* g, u16* l) {
  __builtin_amdgcn_global_load_lds(
      (const __attribute__((address_space(1))) void*)g,
      (__attribute__((address_space(3))) void*)l, 16, 0, 0);
}

// ---------------------------------------------------------------------------
// bf16 MFMA GEMM, double-buffered async staging, BK-wide K-step.
// C[m,n] = epi( sum_k A[m,k]*W[n,k] ); A,W bf16 row-major (MxK / NxK).
// 256 thr = 4 waves (2x2), wave tile (BM/2)x(BN/2), MFMA 16x16x32.
// LDS chunk (lqc, rowgrp): 64 rows x 8 k-cols, staged via global_load_lds
// (lane = row). Frag b128 reads conflict-free (2-way = free).
// EPI: 0 none; 1 +bias; 2 combo (col<512 -> softplus(c+bias), else raw)
// OUTBF: 1 bf16 store, 0 fp32.  BM,BN mult of 64; K mult of BK;
// W must have >= gridDim.y*BN valid rows.
// ---------------------------------------------------------------------------
template<int BM,int BN,int BK,int EPI,int OUTBF>
__global__ __launch_bounds__(256)
void gemm_db(const u16* __restrict__ A, int lda,
             const u16* __restrict__ W, int ldw,
             const float* __restrict__ bias,
             void* __restrict__ Cp, int ldc,
             int N, int K)
{
  constexpr int KS = BK / 32;             // 16x16x32 sub-steps per K-iter
  constexpr int CA = BK / 8;              // 8-col chunks per 64-row group
  constexpr int NCH_A = (BM / 64) * CA;
  constexpr int NCH_B = (BN / 64) * CA;
  constexpr int TI = BM / 2 / 16;
  constexpr int TJ = BN / 2 / 16;

  __shared__ u16 As[2][BM * BK];
  __shared__ u16 Ws[2][BN * BK];

  const int tid = threadIdx.x;
  const int lane = tid & 63;
  const int wv = tid >> 6;
  const int wy = wv >> 1, wx = wv & 1;
  const int rb = wy * (BM / 2);
  const int cb = wx * (BN / 2);
  const int lr = lane & 15, lq = lane >> 4;
  const int bm = blockIdx.x * BM;
  const int bn = blockIdx.y * BN;

  f32x4 acc[TI][TJ];
#pragma unroll
  for (int i = 0; i < TI; ++i)
#pragma unroll
    for (int j = 0; j < TJ; ++j) acc[i][j] = (f32x4){0.f, 0.f, 0.f, 0.f};

  auto stage = [&](int k0, int buf) {
#pragma unroll
    for (int w = wv; w < NCH_A + NCH_B; w += 4) {
      if (w < NCH_A) {
        const int rh = w / CA, lqw = w % CA;
        gll16(A + (size_t)(bm + rh * 64 + lane) * lda + k0 + lqw * 8,
              &As[buf][(lqw * BM + rh * 64) * 8]);
      } else {
        const int w2 = w - NCH_A;
        const int rh = w2 / CA, lqw = w2 % CA;
        gll16(W + (size_t)(bn + rh * 64 + lane) * ldw + k0 + lqw * 8,
              &Ws[buf][(lqw * BN + rh * 64) * 8]);
      }
    }
  };

  stage(0, 0);
  int cur = 0;
  for (int k0 = 0; k0 < K; k0 += BK) {
    __syncthreads();                      // buf[cur] loads drained
    if (k0 + BK < K) stage(k0 + BK, cur ^ 1);

#pragma unroll
    for (int ks = 0; ks < KS; ++ks) {
      const int lqc = ks * 4 + lq;
      bf16x8 af[TI], bf[TJ];
#pragma unroll
      for (int i = 0; i < TI; ++i)
        af[i] = *reinterpret_cast<const bf16x8*>(
                  &As[cur][(lqc * BM + rb + i * 16 + lr) * 8]);
#pragma unroll
      for (int j = 0; j < TJ; ++j)
        bf[j] = *reinterpret_cast<const bf16x8*>(
                  &Ws[cur][(lqc * BN + cb + j * 16 + lr) * 8]);
#pragma unroll
      for (int i = 0; i < TI; ++i)
#pragma unroll
        for (int j = 0; j < TJ; ++j)
          acc[i][j] = __builtin_amdgcn_mfma_f32_16x16x32_bf16(af[i], bf[j], acc[i][j], 0, 0, 0);
    }
    cur ^= 1;
  }

#pragma unroll
  for (int i = 0; i < TI; ++i) {
#pragma unroll
    for (int j = 0; j < TJ; ++j) {
      const int col = bn + cb + j * 16 + lr;
      if (col >= N) continue;
#pragma unroll
      for (int r = 0; r < 4; ++r) {
        const int row = bm + rb + i * 16 + lq * 4 + r;
        float c = acc[i][j][r];
        if (EPI == 1) c += bias[col];
        if (EPI == 2) { if (col < 512) c = softplus_f(c + bias[col]); }
        if (OUTBF) ((u16*)Cp)[(size_t)row * ldc + col] = f2bf(c);
        else       ((float*)Cp)[(size_t)row * ldc + col] = c;
      }
    }
  }
}

// ---------------------------------------------------------------------------
// prep (1728 blocks x 512 thr):
//  blk 0..127   : cast x -> x16
//  blk 128..255 : cast opw (both layers) -> opw16
//  blk 256..383 : cast ipw layer-1 -> ipw16l1
//  blk 384..447 : Wc1[n][enc] = sum_dm ipw0[n][dm]*in_w[dm][enc] (bf16),
//                 bias1[n] = ipw0[n].in_b (lane enc==0)
//  blk 448..1727: wc rows (dt-folded x_proj combo, pad to 640)
// ---------------------------------------------------------------------------
__global__ __launch_bounds__(512)
void prep(const float* __restrict__ x, const float* __restrict__ in_w,
          const float* __restrict__ in_b,
          const float* __restrict__ ipw, const float* __restrict__ opw,
          const float* __restrict__ dtw, const float* __restrict__ xpw,
          u16* __restrict__ x16, u16* __restrict__ opw16,
          u16* __restrict__ ipw16l1, u16* __restrict__ wc1,
          float* __restrict__ bias1, u16* __restrict__ wc)
{
  const int blk = blockIdx.x;
  if (blk < 384) {
    const float* src; u16* dst; int base;
    if (blk < 128)      { src = x;            dst = x16;     base = blk; }
    else if (blk < 256) { src = opw;          dst = opw16;   base = blk - 128; }
    else                { src = ipw + 262144; dst = ipw16l1; base = blk - 256; }
    const int i = (base * 512 + threadIdx.x) * 4;
    float4 v = *reinterpret_cast<const float4*>(src + i);
    u16x4 o;
    o[0] = f2bf(v.x); o[1] = f2bf(v.y); o[2] = f2bf(v.z); o[3] = f2bf(v.w);
    *reinterpret_cast<u16x4*>(dst + i) = o;
  } else if (blk < 448) {
    const int t = threadIdx.x;
    const int n = (blk - 384) * 16 + (t >> 5);
    const int enc = t & 31;
    const float* iprow = ipw + (size_t)n * 256;       // layer 0
    float v = 0.f;
#pragma unroll 8
    for (int j = 0; j < 256; ++j) v = fmaf(iprow[j], in_w[j * 32 + enc], v);
    wc1[n * 32 + enc] = f2bf(v);
    if (enc == 0) {
      float bv = 0.f;
      for (int j = 0; j < 256; ++j) bv = fmaf(iprow[j], in_b[j], bv);
      bias1[n] = bv;
    }
  } else {
    const int idx = blk - 448;
    const int layer = idx / 640;
    const int n = idx % 640;
    const int k = threadIdx.x;
    const float* xp = xpw + (size_t)layer * 48 * 512;
    float v = 0.f;
    if (n < 512) {
      const float* dw = dtw + (size_t)layer * 512 * 16 + n * 16;
#pragma unroll
      for (int r = 0; r < 16; ++r) v = fmaf(dw[r], xp[r * 512 + k], v);
    } else if (n < 544) {
      v = xp[(16 + (n - 512)) * 512 + k];
    }
    wc[((size_t)layer * 640 + n) * 512 + k] = f2bf(v);
  }
}

// ---------------------------------------------------------------------------
// Causal depthwise conv (width 4) + bias + silu. xz bf16 (b,l,1024)[:,:512] -> xc bf16
// ---------------------------------------------------------------------------
__global__ __launch_bounds__(512)
void conv_silu(const u16* __restrict__ xz, const float* __restrict__ cw,
               const float* __restrict__ cb, u16* __restrict__ xc)
{
  const int b = blockIdx.x;          // 8
  const int l0 = blockIdx.y * 32;    // 32 chunks of 32
  const int d = threadIdx.x;         // 512

  const float w0 = cw[d * 4 + 0], w1 = cw[d * 4 + 1];
  const float w2 = cw[d * 4 + 2], w3 = cw[d * 4 + 3];
  const float bias = cb[d];

  const size_t base = ((size_t)b * L_SEQ) * 1024 + d;
  float xm3 = (l0 >= 3) ? bf2f(xz[base + (size_t)(l0 - 3) * 1024]) : 0.f;
  float xm2 = (l0 >= 2) ? bf2f(xz[base + (size_t)(l0 - 2) * 1024]) : 0.f;
  float xm1 = (l0 >= 1) ? bf2f(xz[base + (size_t)(l0 - 1) * 1024]) : 0.f;

#pragma unroll 4
  for (int i = 0; i < 32; ++i) {
    const int l = l0 + i;
    const float x0 = bf2f(xz[base + (size_t)l * 1024]);
    const float v = bias + w0 * xm3 + w1 * xm2 + w2 * xm1 + w3 * x0;
    xc[((size_t)b * L_SEQ + l) * 512 + d] = f2bf(silu_f(v));
    xm3 = xm2; xm2 = xm1; xm1 = x0;
  }
}

// ---------------------------------------------------------------------------
// Scan pass A + fused mid: per-chunk aggregates (Ac = prod dA, Bc = local h),
// then the LAST-arriving block per (b,dgrp) computes the exclusive-prefix
// chunk states Hin for its d-range (device-scope atomics + fences).
// ---------------------------------------------------------------------------
__global__ __launch_bounds__(256)
void scan_passA(const float* __restrict__ xo, const u16* __restrict__ u,
                const float* __restrict__ Alog,
                float* __restrict__ Ac, float* __restrict__ Bc,
                float* __restrict__ Hin, unsigned* __restrict__ cnt)
{
  const int b = blockIdx.x;
  const int d = blockIdx.y * 256 + threadIdx.x;
  const int c = blockIdx.z;
  const int t0 = c * TCHUNK;

  __shared__ float sB[TCHUNK][16];
#pragma unroll
  for (int r = 0; r < TCHUNK * 16; r += 256) {
    const int e = threadIdx.x + r;
    const int t = e >> 4, n = e & 15;
    sB[t][n] = xo[((size_t)b * L_SEQ + t0 + t) * 544 + 512 + n];
  }
  __syncthreads();

  float A[16], h[16], p[16];
  const float* al = Alog + d * 16;
#pragma unroll
  for (int n = 0; n < 16; ++n) { A[n] = -__expf(al[n]); h[n] = 0.f; p[n] = 1.f; }

#pragma unroll 2
  for (int t = 0; t < TCHUNK; ++t) {
    const size_t row = (size_t)b * L_SEQ + t0 + t;
    const float dtv = xo[row * 544 + d];
    const float uv  = bf2f(u[row * 512 + d]);
    const float cf  = dtv * uv;
    const f32x4* Bq = reinterpret_cast<const f32x4*>(&sB[t][0]);
#pragma unroll
    for (int q = 0; q < 4; ++q) {
      const f32x4 Bv = Bq[q];
#pragma unroll
      for (int k = 0; k < 4; ++k) {
        const int n = q * 4 + k;
        const float dA = __expf(dtv * A[n]);
        p[n] *= dA;
        h[n] = fmaf(dA, h[n], cf * Bv[k]);
      }
    }
  }

  float* ac = Ac + (((size_t)b * NCHUNK + c) * 512 + d) * 16;
  float* bc = Bc + (((size_t)b * NCHUNK + c) * 512 + d) * 16;
#pragma unroll
  for (int q = 0; q < 4; ++q) {
    f32x4 va, vb;
#pragma unroll
    for (int k = 0; k < 4; ++k) { va[k] = p[q * 4 + k]; vb[k] = h[q * 4 + k]; }
    reinterpret_cast<f32x4*>(ac)[q] = va;
    reinterpret_cast<f32x4*>(bc)[q] = vb;
  }

  // ---- last-block-arrival: compute Hin for this (b, dgrp) ----
  __syncthreads();
  __shared__ unsigned lastf;
  if (threadIdx.x == 0) {
    __threadfence();                       // make Ac/Bc visible device-wide
    unsigned old = atomicAdd(&cnt[b * 2 + blockIdx.y], 1u);
    lastf = (old == NCHUNK - 1) ? 1u : 0u;
  }
  __syncthreads();
  if (lastf) {
    __threadfence();                       // acquire other blocks' Ac/Bc
    float hh[16];
#pragma unroll
    for (int n = 0; n < 16; ++n) hh[n] = 0.f;
    for (int cc = 0; cc < NCHUNK; ++cc) {
      const size_t base2 = (((size_t)b * NCHUNK + cc) * 512 + d) * 16;
#pragma unroll
      for (int q = 0; q < 4; ++q) {
        const f32x4 va = reinterpret_cast<const f32x4*>(Ac + base2)[q];
        const f32x4 vb = reinterpret_cast<const f32x4*>(Bc + base2)[q];
        f32x4 ho;
#pragma unroll
        for (int k = 0; k < 4; ++k) {
          ho[k] = hh[q * 4 + k];
          hh[q * 4 + k] = fmaf(va[k], hh[q * 4 + k], vb[k]);
        }
        reinterpret_cast<f32x4*>(Hin + base2)[q] = ho;
      }
    }
  }
}

// ---------------------------------------------------------------------------
// Scan pass B: seeded full scan per chunk; writes yg = (y + u*D) * silu(z)
// as bf16 into the u buffer (read-before-write per element).
// ---------------------------------------------------------------------------
__global__ __launch_bounds__(256)
void scan_passB(const float* __restrict__ xo, const u16* __restrict__ u,
                const u16* __restrict__ xz,
                const float* __restrict__ Alog, const float* __restrict__ Dsk,
                const float* __restrict__ Hin, u16* __restrict__ yg)
{
  const int b = blockIdx.x;
  const int d = blockIdx.y * 256 + threadIdx.x;
  const int c = blockIdx.z;
  const int t0 = c * TCHUNK;

  __shared__ float sB[TCHUNK][16], sC[TCHUNK][16];
#pragma unroll
  for (int r = 0; r < TCHUNK * 16; r += 256) {
    const int e = threadIdx.x + r;
    const int t = e >> 4, n = e & 15;
    const size_t row = (size_t)b * L_SEQ + t0 + t;
    sB[t][n] = xo[row * 544 + 512 + n];
    sC[t][n] = xo[row * 544 + 528 + n];
  }
  __syncthreads();

  float A[16], h[16];
  const float* al = Alog + d * 16;
#pragma unroll
  for (int n = 0; n < 16; ++n) A[n] = -__expf(al[n]);

  const float* hp = Hin + (((size_t)b * NCHUNK + c) * 512 + d) * 16;
#pragma unroll
  for (int q = 0; q < 4; ++q) {
    const f32x4 v = reinterpret_cast<const f32x4*>(hp)[q];
#pragma unroll
    for (int k = 0; k < 4; ++k) h[q * 4 + k] = v[k];
  }

  const float Dv = Dsk[d];

#pragma unroll 2
  for (int t = 0; t < TCHUNK; ++t) {
    const size_t row = (size_t)b * L_SEQ + t0 + t;
    const float dtv = xo[row * 544 + d];
    const float uv  = bf2f(u[row * 512 + d]);
    const float zf  = bf2f(xz[row * 1024 + 512 + d]);
    const float cf  = dtv * uv;
    const f32x4* Bq = reinterpret_cast<const f32x4*>(&sB[t][0]);
    const f32x4* Cq = reinterpret_cast<const f32x4*>(&sC[t][0]);
    float s0 = 0.f, s1 = 0.f, s2 = 0.f, s3 = 0.f;
#pragma unroll
    for (int q = 0; q < 4; ++q) {
      const f32x4 Bv = Bq[q];
      const f32x4 Cv = Cq[q];
#pragma unroll
      for (int k = 0; k < 4; ++k) {
        const int n = q * 4 + k;
        const float dA = __expf(dtv * A[n]);
        h[n] = fmaf(dA, h[n], cf * Bv[k]);
      }
      s0 = fmaf(h[q * 4 + 0], Cv[0], s0);
      s1 = fmaf(h[q * 4 + 1], Cv[1], s1);
      s2 = fmaf(h[q * 4 + 2], Cv[2], s2);
      s3 = fmaf(h[q * 4 + 3], Cv[3], s3);
    }
    const float yv = fmaf(uv, Dv, (s0 + s1) + (s2 + s3));
    yg[row * 512 + d] = f2bf(yv * silu_f(zf));
  }
}

// ---------------------------------------------------------------------------
// Fused head: one block per batch. g[f] = gelu(h_last.p1w[f]+p1b[f]);
// out[b] = sum_f g[f]*p2w[f] + p2b.
// ---------------------------------------------------------------------------
__global__ __launch_bounds__(1024)
void head(const u16* __restrict__ h, const float* __restrict__ p1w,
          const float* __restrict__ p1b, const float* __restrict__ p2w,
          const float* __restrict__ p2b, float* __restrict__ out)
{
  const int b = blockIdx.x;
  const int f = threadIdx.x;

  __shared__ float hl[256];
  if (f < 256) hl[f] = bf2f(h[((size_t)b * L_SEQ + (L_SEQ - 1)) * 256 + f]);
  __syncthreads();

  const float* wr = p1w + (size_t)f * 256;
  float acc = 0.f;
#pragma unroll 8
  for (int k = 0; k < 256; k += 4) {
    float4 wv = *reinterpret_cast<const float4*>(wr + k);
    acc = fmaf(hl[k + 0], wv.x, acc);
    acc = fmaf(hl[k + 1], wv.y, acc);
    acc = fmaf(hl[k + 2], wv.z, acc);
    acc = fmaf(hl[k + 3], wv.w, acc);
  }
  const float xv = acc + p1b[f];
  const float gg = 0.5f * xv * (1.f + erff(xv * 0.70710678118654752f));
  float s = gg * p2w[f];

  s += __shfl_xor(s, 1);
  s += __shfl_xor(s, 2);
  s += __shfl_xor(s, 4);
  s += __shfl_xor(s, 8);
  s += __shfl_xor(s, 16);
  s += __shfl_xor(s, 32);
  __shared__ float red[16];
  if ((f & 63) == 0) red[f >> 6] = s;
  __syncthreads();
  if (f == 0) {
    float t = 0.f;
#pragma unroll
    for (int i = 0; i < 16; ++i) t += red[i];
    out[b] = t + p2b[0];
  }
}

// ---------------------------------------------------------------------------
extern "C" void kernel_launch(void* const* d_in, const int* in_sizes, int n_in,
                              void* d_out, int out_size, void* d_ws, size_t ws_size,
                              hipStream_t stream)
{
  const float* x    = (const float*)d_in[0];
  const float* in_w = (const float*)d_in[1];
  const float* in_b = (const float*)d_in[2];
  const float* ipw  = (const float*)d_in[3];
  const float* cw   = (const float*)d_in[4];
  const float* cb   = (const float*)d_in[5];
  const float* xpw  = (const float*)d_in[6];
  const float* dtw  = (const float*)d_in[7];
  const float* dtb  = (const float*)d_in[8];
  const float* Alog = (const float*)d_in[9];
  const float* Dsk  = (const float*)d_in[10];
  const float* opw  = (const float*)d_in[11];
  const float* p1w  = (const float*)d_in[12];
  const float* p1b  = (const float*)d_in[13];
  const float* p2w  = (const float*)d_in[14];
  const float* p2b  = (const float*)d_in[15];

  float* ws = (float*)d_ws;
  // layout (fp32-word offsets)
  u16*   h16  = (u16*)(ws);                 // 8192*256  bf16 -> 1,048,576 fw
  u16*   xz16 = (u16*)(ws + 1048576);       // 8192*1024 bf16 -> 4,194,304 fw
  u16*   xc16 = (u16*)(ws + 5242880);       // 8192*512  bf16 -> 2,097,152 fw
  float* xo   = ws + 7340032;               // 8192*544  f32  -> 4,456,448 fw
  u16*   wc16 = (u16*)(ws + 11796480);      // 2*640*512 bf16 ->   327,680 fw
  u16*   wbf  = (u16*)(ws + 12124160);      // casts: 786432 u16 -> 393,216 fw
  float* Ac   = ws + 12660736;              // 8*32*512*16 f32 -> 2,097,152 fw
  float* Bc   = ws + 14757888;              // 2,097,152 fw
  float* Hin  = ws + 16855040;              // 2,097,152 fw
  u16*   wc1  = (u16*)(ws + 18952192);      // 1024*32 bf16 -> 16,384 fw
  float* bias1 = ws + 18968576;             // 1024 fw
  unsigned* cnt = (unsigned*)(ws + 18969600); // 32 u32 (16 per layer)
  // end ~18,969,616 fw ~= 75.9 MB

  u16* x16     = wbf;                       // 262,144
  u16* opw16   = wbf + 262144;              // 262,144 (both layers)
  u16* ipw16l1 = wbf + 524288;              // 262,144 (layer 1 only)

  hipMemsetAsync(cnt, 0, 32 * sizeof(unsigned), stream);

  prep<<<1728, 512, 0, stream>>>(x, in_w, in_b, ipw, opw, dtw, xpw,
                                 x16, opw16, ipw16l1, wc1, bias1, wc16);

  // ---------------- layer 0 (embed folded: K=32) ----------------
  {
    const float* cw_l  = cw;
    const float* cb_l  = cb;
    const float* dtb_l = dtb;
    const float* Al_l  = Alog;
    const float* Dsk_l = Dsk;
    const u16*   opw_l = opw16;
    const u16*   wc_l  = wc16;

    // xz = x @ Wc1^T + bias1  (M=8192,N=1024,K=32) -> bf16
    gemm_db<64, 128, 32, 1, 1><<<dim3(M_ROWS / 64, 8), 256, 0, stream>>>(
        x16, 32, wc1, 32, bias1, xz16, 1024, 1024, 32);

    conv_silu<<<dim3(8, 32), 512, 0, stream>>>(xz16, cw_l, cb_l, xc16);

    gemm_db<64, 128, 64, 2, 0><<<dim3(M_ROWS / 64, 5), 256, 0, stream>>>(
        xc16, 512, wc_l, 512, dtb_l, xo, 544, 544, 512);

    scan_passA<<<dim3(8, 2, NCHUNK), 256, 0, stream>>>(
        xo, xc16, Al_l, Ac, Bc, Hin, cnt);
    scan_passB<<<dim3(8, 2, NCHUNK), 256, 0, stream>>>(
        xo, xc16, xz16, Al_l, Dsk_l, Hin, xc16);

    gemm_db<64, 64, 64, 0, 1><<<dim3(M_ROWS / 64, 4), 256, 0, stream>>>(
        xc16, 512, opw_l, 512, nullptr, h16, 256, 256, 512);
  }

  // ---------------- layer 1 ----------------
  {
    const float* cw_l  = cw  + 512 * 4;
    const float* cb_l  = cb  + 512;
    const float* dtb_l = dtb + 512;
    const float* Al_l  = Alog + 512 * 16;
    const float* Dsk_l = Dsk + 512;
    const u16*   opw_l = opw16 + 256 * 512;
    const u16*   wc_l  = wc16 + 640 * 512;

    // xz = h @ ipw^T  (N=1024,K=256) -> bf16
    gemm_db<64, 128, 64, 0, 1><<<dim3(M_ROWS / 64, 8), 256, 0, stream>>>(
        h16, 256, ipw16l1, 256, nullptr, xz16, 1024, 1024, 256);

    conv_silu<<<dim3(8, 32), 512, 0, stream>>>(xz16, cw_l, cb_l, xc16);

    gemm_db<64, 128, 64, 2, 0><<<dim3(M_ROWS / 64, 5), 256, 0, stream>>>(
        xc16, 512, wc_l, 512, dtb_l, xo, 544, 544, 512);

    scan_passA<<<dim3(8, 2, NCHUNK), 256, 0, stream>>>(
        xo, xc16, Al_l, Ac, Bc, Hin, cnt + 16);
    scan_passB<<<dim3(8, 2, NCHUNK), 256, 0, stream>>>(
        xo, xc16, xz16, Al_l, Dsk_l, Hin, xc16);

    gemm_db<64, 64, 64, 0, 1><<<dim3(M_ROWS / 64, 4), 256, 0, stream>>>(
        xc16, 512, opw_l, 512, nullptr, h16, 256, 256, 512);
  }

  head<<<8, 1024, 0, stream>>>(h16, p1w, p1b, p2w, p2b, (float*)d_out);
}

// Round 9
// 370.078 us; speedup vs baseline: 1.2636x; 1.2636x over previous
//
#include <hip/hip_runtime.h>
#include <math.h>

// ---------------------------------------------------------------------------
// Mamba forward. Round 9: R8 minus the scan fusion regression.
//  - scan_mid restored as its own tiny kernel (R8's last-block-arrival fusion
//    cost +138us: per-block device fences + drained-GPU serial tail)
//  - kept from R8: BK=64 dbuf GEMMs, embed folded into L0 in_proj (K=32),
//    merged prep, fused head
// Shapes: B=8 L=1024 ENC=32 DM=256 DI=512 DS=16 DC=4 DTR=16 LAYERS=2 DFF=1024
// ---------------------------------------------------------------------------

static constexpr int L_SEQ = 1024;
static constexpr int M_ROWS = 8 * 1024;   // B*L
static constexpr int NCHUNK = 32;
static constexpr int TCHUNK = 32;         // L_SEQ / NCHUNK

typedef unsigned short u16;
typedef unsigned short u16x8 __attribute__((ext_vector_type(8)));
typedef unsigned short u16x4 __attribute__((ext_vector_type(4)));
typedef short bf16x8 __attribute__((ext_vector_type(8)));   // MFMA operand type
typedef float f32x4 __attribute__((ext_vector_type(4)));

__device__ __forceinline__ float silu_f(float x) { return x / (1.f + __expf(-x)); }
__device__ __forceinline__ float softplus_f(float x) {
  return (x > 20.f) ? x : log1pf(__expf(x));
}
__device__ __forceinline__ u16 f2bf(float f) {          // RNE fp32->bf16
  unsigned u = __builtin_bit_cast(unsigned, f);
  u += 0x7FFFu + ((u >> 16) & 1u);
  return (u16)(u >> 16);
}
__device__ __forceinline__ float bf2f(u16 v) {
  return __builtin_bit_cast(float, (unsigned)v << 16);
}

// async global->LDS, 16 B per lane; LDS dest = uniform base + lane*16
__device__ __forceinline__ void gll16(const u16* g, u16* l) {
  __builtin_amdgcn_global_load_lds(
      (const __attribute__((address_space(1))) void*)g,
      (__attribute__((address_space(3))) void*)l, 16, 0, 0);
}

// ---------------------------------------------------------------------------
// bf16 MFMA GEMM, double-buffered async staging, BK-wide K-step.
// C[m,n] = epi( sum_k A[m,k]*W[n,k] ); A,W bf16 row-major (MxK / NxK).
// 256 thr = 4 waves (2x2), wave tile (BM/2)x(BN/2), MFMA 16x16x32.
// EPI: 0 none; 1 +bias; 2 combo (col<512 -> softplus(c+bias), else raw)
// OUTBF: 1 bf16 store, 0 fp32.  BM,BN mult of 64; K mult of BK;
// W must have >= gridDim.y*BN valid rows.
// ---------------------------------------------------------------------------
template<int BM,int BN,int BK,int EPI,int OUTBF>
__global__ __launch_bounds__(256)
void gemm_db(const u16* __restrict__ A, int lda,
             const u16* __restrict__ W, int ldw,
             const float* __restrict__ bias,
             void* __restrict__ Cp, int ldc,
             int N, int K)
{
  constexpr int KS = BK / 32;             // 16x16x32 sub-steps per K-iter
  constexpr int CA = BK / 8;              // 8-col chunks per 64-row group
  constexpr int NCH_A = (BM / 64) * CA;
  constexpr int NCH_B = (BN / 64) * CA;
  constexpr int TI = BM / 2 / 16;
  constexpr int TJ = BN / 2 / 16;

  __shared__ u16 As[2][BM * BK];
  __shared__ u16 Ws[2][BN * BK];

  const int tid = threadIdx.x;
  const int lane = tid & 63;
  const int wv = tid >> 6;
  const int wy = wv >> 1, wx = wv & 1;
  const int rb = wy * (BM / 2);
  const int cb = wx * (BN / 2);
  const int lr = lane & 15, lq = lane >> 4;
  const int bm = blockIdx.x * BM;
  const int bn = blockIdx.y * BN;

  f32x4 acc[TI][TJ];
#pragma unroll
  for (int i = 0; i < TI; ++i)
#pragma unroll
    for (int j = 0; j < TJ; ++j) acc[i][j] = (f32x4){0.f, 0.f, 0.f, 0.f};

  auto stage = [&](int k0, int buf) {
#pragma unroll
    for (int w = wv; w < NCH_A + NCH_B; w += 4) {
      if (w < NCH_A) {
        const int rh = w / CA, lqw = w % CA;
        gll16(A + (size_t)(bm + rh * 64 + lane) * lda + k0 + lqw * 8,
              &As[buf][(lqw * BM + rh * 64) * 8]);
      } else {
        const int w2 = w - NCH_A;
        const int rh = w2 / CA, lqw = w2 % CA;
        gll16(W + (size_t)(bn + rh * 64 + lane) * ldw + k0 + lqw * 8,
              &Ws[buf][(lqw * BN + rh * 64) * 8]);
      }
    }
  };

  stage(0, 0);
  int cur = 0;
  for (int k0 = 0; k0 < K; k0 += BK) {
    __syncthreads();                      // buf[cur] loads drained
    if (k0 + BK < K) stage(k0 + BK, cur ^ 1);

#pragma unroll
    for (int ks = 0; ks < KS; ++ks) {
      const int lqc = ks * 4 + lq;
      bf16x8 af[TI], bf[TJ];
#pragma unroll
      for (int i = 0; i < TI; ++i)
        af[i] = *reinterpret_cast<const bf16x8*>(
                  &As[cur][(lqc * BM + rb + i * 16 + lr) * 8]);
#pragma unroll
      for (int j = 0; j < TJ; ++j)
        bf[j] = *reinterpret_cast<const bf16x8*>(
                  &Ws[cur][(lqc * BN + cb + j * 16 + lr) * 8]);
#pragma unroll
      for (int i = 0; i < TI; ++i)
#pragma unroll
        for (int j = 0; j < TJ; ++j)
          acc[i][j] = __builtin_amdgcn_mfma_f32_16x16x32_bf16(af[i], bf[j], acc[i][j], 0, 0, 0);
    }
    cur ^= 1;
  }

#pragma unroll
  for (int i = 0; i < TI; ++i) {
#pragma unroll
    for (int j = 0; j < TJ; ++j) {
      const int col = bn + cb + j * 16 + lr;
      if (col >= N) continue;
#pragma unroll
      for (int r = 0; r < 4; ++r) {
        const int row = bm + rb + i * 16 + lq * 4 + r;
        float c = acc[i][j][r];
        if (EPI == 1) c += bias[col];
        if (EPI == 2) { if (col < 512) c = softplus_f(c + bias[col]); }
        if (OUTBF) ((u16*)Cp)[(size_t)row * ldc + col] = f2bf(c);
        else       ((float*)Cp)[(size_t)row * ldc + col] = c;
      }
    }
  }
}

// ---------------------------------------------------------------------------
// prep (1728 blocks x 512 thr):
//  blk 0..127   : cast x -> x16
//  blk 128..255 : cast opw (both layers) -> opw16
//  blk 256..383 : cast ipw layer-1 -> ipw16l1
//  blk 384..447 : Wc1[n][enc] = sum_dm ipw0[n][dm]*in_w[dm][enc] (bf16),
//                 bias1[n] = ipw0[n].in_b (lane enc==0)
//  blk 448..1727: wc rows (dt-folded x_proj combo, pad to 640)
// ---------------------------------------------------------------------------
__global__ __launch_bounds__(512)
void prep(const float* __restrict__ x, const float* __restrict__ in_w,
          const float* __restrict__ in_b,
          const float* __restrict__ ipw, const float* __restrict__ opw,
          const float* __restrict__ dtw, const float* __restrict__ xpw,
          u16* __restrict__ x16, u16* __restrict__ opw16,
          u16* __restrict__ ipw16l1, u16* __restrict__ wc1,
          float* __restrict__ bias1, u16* __restrict__ wc)
{
  const int blk = blockIdx.x;
  if (blk < 384) {
    const float* src; u16* dst; int base;
    if (blk < 128)      { src = x;            dst = x16;     base = blk; }
    else if (blk < 256) { src = opw;          dst = opw16;   base = blk - 128; }
    else                { src = ipw + 262144; dst = ipw16l1; base = blk - 256; }
    const int i = (base * 512 + threadIdx.x) * 4;
    float4 v = *reinterpret_cast<const float4*>(src + i);
    u16x4 o;
    o[0] = f2bf(v.x); o[1] = f2bf(v.y); o[2] = f2bf(v.z); o[3] = f2bf(v.w);
    *reinterpret_cast<u16x4*>(dst + i) = o;
  } else if (blk < 448) {
    const int t = threadIdx.x;
    const int n = (blk - 384) * 16 + (t >> 5);
    const int enc = t & 31;
    const float* iprow = ipw + (size_t)n * 256;       // layer 0
    float v = 0.f;
#pragma unroll 8
    for (int j = 0; j < 256; ++j) v = fmaf(iprow[j], in_w[j * 32 + enc], v);
    wc1[n * 32 + enc] = f2bf(v);
    if (enc == 0) {
      float bv = 0.f;
      for (int j = 0; j < 256; ++j) bv = fmaf(iprow[j], in_b[j], bv);
      bias1[n] = bv;
    }
  } else {
    const int idx = blk - 448;
    const int layer = idx / 640;
    const int n = idx % 640;
    const int k = threadIdx.x;
    const float* xp = xpw + (size_t)layer * 48 * 512;
    float v = 0.f;
    if (n < 512) {
      const float* dw = dtw + (size_t)layer * 512 * 16 + n * 16;
#pragma unroll
      for (int r = 0; r < 16; ++r) v = fmaf(dw[r], xp[r * 512 + k], v);
    } else if (n < 544) {
      v = xp[(16 + (n - 512)) * 512 + k];
    }
    wc[((size_t)layer * 640 + n) * 512 + k] = f2bf(v);
  }
}

// ---------------------------------------------------------------------------
// Causal depthwise conv (width 4) + bias + silu. xz bf16 (b,l,1024)[:,:512] -> xc bf16
// ---------------------------------------------------------------------------
__global__ __launch_bounds__(512)
void conv_silu(const u16* __restrict__ xz, const float* __restrict__ cw,
               const float* __restrict__ cb, u16* __restrict__ xc)
{
  const int b = blockIdx.x;          // 8
  const int l0 = blockIdx.y * 32;    // 32 chunks of 32
  const int d = threadIdx.x;         // 512

  const float w0 = cw[d * 4 + 0], w1 = cw[d * 4 + 1];
  const float w2 = cw[d * 4 + 2], w3 = cw[d * 4 + 3];
  const float bias = cb[d];

  const size_t base = ((size_t)b * L_SEQ) * 1024 + d;
  float xm3 = (l0 >= 3) ? bf2f(xz[base + (size_t)(l0 - 3) * 1024]) : 0.f;
  float xm2 = (l0 >= 2) ? bf2f(xz[base + (size_t)(l0 - 2) * 1024]) : 0.f;
  float xm1 = (l0 >= 1) ? bf2f(xz[base + (size_t)(l0 - 1) * 1024]) : 0.f;

#pragma unroll 4
  for (int i = 0; i < 32; ++i) {
    const int l = l0 + i;
    const float x0 = bf2f(xz[base + (size_t)l * 1024]);
    const float v = bias + w0 * xm3 + w1 * xm2 + w2 * xm1 + w3 * x0;
    xc[((size_t)b * L_SEQ + l) * 512 + d] = f2bf(silu_f(v));
    xm3 = xm2; xm2 = xm1; xm1 = x0;
  }
}

// ---------------------------------------------------------------------------
// Scan pass A: per-chunk aggregates. One thread per d; h[16]/p[16] in regs;
// B chunk staged in LDS (b128 broadcast reads). Ac = prod dA, Bc = local h.
// ---------------------------------------------------------------------------
__global__ __launch_bounds__(256)
void scan_passA(const float* __restrict__ xo, const u16* __restrict__ u,
                const float* __restrict__ Alog,
                float* __restrict__ Ac, float* __restrict__ Bc)
{
  const int b = blockIdx.x;
  const int d = blockIdx.y * 256 + threadIdx.x;
  const int c = blockIdx.z;
  const int t0 = c * TCHUNK;

  __shared__ float sB[TCHUNK][16];
#pragma unroll
  for (int r = 0; r < TCHUNK * 16; r += 256) {
    const int e = threadIdx.x + r;
    const int t = e >> 4, n = e & 15;
    sB[t][n] = xo[((size_t)b * L_SEQ + t0 + t) * 544 + 512 + n];
  }
  __syncthreads();

  float A[16], h[16], p[16];
  const float* al = Alog + d * 16;
#pragma unroll
  for (int n = 0; n < 16; ++n) { A[n] = -__expf(al[n]); h[n] = 0.f; p[n] = 1.f; }

#pragma unroll 2
  for (int t = 0; t < TCHUNK; ++t) {
    const size_t row = (size_t)b * L_SEQ + t0 + t;
    const float dtv = xo[row * 544 + d];
    const float uv  = bf2f(u[row * 512 + d]);
    const float cf  = dtv * uv;
    const f32x4* Bq = reinterpret_cast<const f32x4*>(&sB[t][0]);
#pragma unroll
    for (int q = 0; q < 4; ++q) {
      const f32x4 Bv = Bq[q];
#pragma unroll
      for (int k = 0; k < 4; ++k) {
        const int n = q * 4 + k;
        const float dA = __expf(dtv * A[n]);
        p[n] *= dA;
        h[n] = fmaf(dA, h[n], cf * Bv[k]);
      }
    }
  }

  float* ac = Ac + (((size_t)b * NCHUNK + c) * 512 + d) * 16;
  float* bc = Bc + (((size_t)b * NCHUNK + c) * 512 + d) * 16;
#pragma unroll
  for (int q = 0; q < 4; ++q) {
    f32x4 va, vb;
#pragma unroll
    for (int k = 0; k < 4; ++k) { va[k] = p[q * 4 + k]; vb[k] = h[q * 4 + k]; }
    reinterpret_cast<f32x4*>(ac)[q] = va;
    reinterpret_cast<f32x4*>(bc)[q] = vb;
  }
}

// ---------------------------------------------------------------------------
// Scan mid: exclusive-prefix chunk states. One thread per (b,d,n).
// ---------------------------------------------------------------------------
__global__ __launch_bounds__(256)
void scan_mid(const float* __restrict__ Ac, const float* __restrict__ Bc,
              float* __restrict__ Hin)
{
  const int gid = blockIdx.x * 256 + threadIdx.x;   // 65536 = 8*512*16
  const int b = gid >> 13;
  const int e = gid & 8191;                          // d*16 + n
  float h = 0.f;
  for (int c = 0; c < NCHUNK; ++c) {
    const size_t idx = ((size_t)(b * NCHUNK + c)) * 8192 + e;
    Hin[idx] = h;
    h = fmaf(Ac[idx], h, Bc[idx]);
  }
}

// ---------------------------------------------------------------------------
// Scan pass B: seeded full scan per chunk; writes yg = (y + u*D) * silu(z)
// as bf16 into the u buffer (read-before-write per element).
// ---------------------------------------------------------------------------
__global__ __launch_bounds__(256)
void scan_passB(const float* __restrict__ xo, const u16* __restrict__ u,
                const u16* __restrict__ xz,
                const float* __restrict__ Alog, const float* __restrict__ Dsk,
                const float* __restrict__ Hin, u16* __restrict__ yg)
{
  const int b = blockIdx.x;
  const int d = blockIdx.y * 256 + threadIdx.x;
  const int c = blockIdx.z;
  const int t0 = c * TCHUNK;

  __shared__ float sB[TCHUNK][16], sC[TCHUNK][16];
#pragma unroll
  for (int r = 0; r < TCHUNK * 16; r += 256) {
    const int e = threadIdx.x + r;
    const int t = e >> 4, n = e & 15;
    const size_t row = (size_t)b * L_SEQ + t0 + t;
    sB[t][n] = xo[row * 544 + 512 + n];
    sC[t][n] = xo[row * 544 + 528 + n];
  }
  __syncthreads();

  float A[16], h[16];
  const float* al = Alog + d * 16;
#pragma unroll
  for (int n = 0; n < 16; ++n) A[n] = -__expf(al[n]);

  const float* hp = Hin + (((size_t)b * NCHUNK + c) * 512 + d) * 16;
#pragma unroll
  for (int q = 0; q < 4; ++q) {
    const f32x4 v = reinterpret_cast<const f32x4*>(hp)[q];
#pragma unroll
    for (int k = 0; k < 4; ++k) h[q * 4 + k] = v[k];
  }

  const float Dv = Dsk[d];

#pragma unroll 2
  for (int t = 0; t < TCHUNK; ++t) {
    const size_t row = (size_t)b * L_SEQ + t0 + t;
    const float dtv = xo[row * 544 + d];
    const float uv  = bf2f(u[row * 512 + d]);
    const float zf  = bf2f(xz[row * 1024 + 512 + d]);
    const float cf  = dtv * uv;
    const f32x4* Bq = reinterpret_cast<const f32x4*>(&sB[t][0]);
    const f32x4* Cq = reinterpret_cast<const f32x4*>(&sC[t][0]);
    float s0 = 0.f, s1 = 0.f, s2 = 0.f, s3 = 0.f;
#pragma unroll
    for (int q = 0; q < 4; ++q) {
      const f32x4 Bv = Bq[q];
      const f32x4 Cv = Cq[q];
#pragma unroll
      for (int k = 0; k < 4; ++k) {
        const int n = q * 4 + k;
        const float dA = __expf(dtv * A[n]);
        h[n] = fmaf(dA, h[n], cf * Bv[k]);
      }
      s0 = fmaf(h[q * 4 + 0], Cv[0], s0);
      s1 = fmaf(h[q * 4 + 1], Cv[1], s1);
      s2 = fmaf(h[q * 4 + 2], Cv[2], s2);
      s3 = fmaf(h[q * 4 + 3], Cv[3], s3);
    }
    const float yv = fmaf(uv, Dv, (s0 + s1) + (s2 + s3));
    yg[row * 512 + d] = f2bf(yv * silu_f(zf));
  }
}

// ---------------------------------------------------------------------------
// Fused head: one block per batch. g[f] = gelu(h_last.p1w[f]+p1b[f]);
// out[b] = sum_f g[f]*p2w[f] + p2b.
// ---------------------------------------------------------------------------
__global__ __launch_bounds__(1024)
void head(const u16* __restrict__ h, const float* __restrict__ p1w,
          const float* __restrict__ p1b, const float* __restrict__ p2w,
          const float* __restrict__ p2b, float* __restrict__ out)
{
  const int b = blockIdx.x;
  const int f = threadIdx.x;

  __shared__ float hl[256];
  if (f < 256) hl[f] = bf2f(h[((size_t)b * L_SEQ + (L_SEQ - 1)) * 256 + f]);
  __syncthreads();

  const float* wr = p1w + (size_t)f * 256;
  float acc = 0.f;
#pragma unroll 8
  for (int k = 0; k < 256; k += 4) {
    float4 wv = *reinterpret_cast<const float4*>(wr + k);
    acc = fmaf(hl[k + 0], wv.x, acc);
    acc = fmaf(hl[k + 1], wv.y, acc);
    acc = fmaf(hl[k + 2], wv.z, acc);
    acc = fmaf(hl[k + 3], wv.w, acc);
  }
  const float xv = acc + p1b[f];
  const float gg = 0.5f * xv * (1.f + erff(xv * 0.70710678118654752f));
  float s = gg * p2w[f];

  s += __shfl_xor(s, 1);
  s += __shfl_xor(s, 2);
  s += __shfl_xor(s, 4);
  s += __shfl_xor(s, 8);
  s += __shfl_xor(s, 16);
  s += __shfl_xor(s, 32);
  __shared__ float red[16];
  if ((f & 63) == 0) red[f >> 6] = s;
  __syncthreads();
  if (f == 0) {
    float t = 0.f;
#pragma unroll
    for (int i = 0; i < 16; ++i) t += red[i];
    out[b] = t + p2b[0];
  }
}

// ---------------------------------------------------------------------------
extern "C" void kernel_launch(void* const* d_in, const int* in_sizes, int n_in,
                              void* d_out, int out_size, void* d_ws, size_t ws_size,
                              hipStream_t stream)
{
  const float* x    = (const float*)d_in[0];
  const float* in_w = (const float*)d_in[1];
  const float* in_b = (const float*)d_in[2];
  const float* ipw  = (const float*)d_in[3];
  const float* cw   = (const float*)d_in[4];
  const float* cb   = (const float*)d_in[5];
  const float* xpw  = (const float*)d_in[6];
  const float* dtw  = (const float*)d_in[7];
  const float* dtb  = (const float*)d_in[8];
  const float* Alog = (const float*)d_in[9];
  const float* Dsk  = (const float*)d_in[10];
  const float* opw  = (const float*)d_in[11];
  const float* p1w  = (const float*)d_in[12];
  const float* p1b  = (const float*)d_in[13];
  const float* p2w  = (const float*)d_in[14];
  const float* p2b  = (const float*)d_in[15];

  float* ws = (float*)d_ws;
  // layout (fp32-word offsets)
  u16*   h16  = (u16*)(ws);                 // 8192*256  bf16 -> 1,048,576 fw
  u16*   xz16 = (u16*)(ws + 1048576);       // 8192*1024 bf16 -> 4,194,304 fw
  u16*   xc16 = (u16*)(ws + 5242880);       // 8192*512  bf16 -> 2,097,152 fw
  float* xo   = ws + 7340032;               // 8192*544  f32  -> 4,456,448 fw
  u16*   wc16 = (u16*)(ws + 11796480);      // 2*640*512 bf16 ->   327,680 fw
  u16*   wbf  = (u16*)(ws + 12124160);      // casts: 786432 u16 -> 393,216 fw
  float* Ac   = ws + 12660736;              // 8*32*512*16 f32 -> 2,097,152 fw
  float* Bc   = ws + 14757888;              // 2,097,152 fw
  float* Hin  = ws + 16855040;              // 2,097,152 fw
  u16*   wc1  = (u16*)(ws + 18952192);      // 1024*32 bf16 -> 16,384 fw
  float* bias1 = ws + 18968576;             // 1024 fw
  // end ~18,969,600 fw ~= 75.9 MB

  u16* x16     = wbf;                       // 262,144
  u16* opw16   = wbf + 262144;              // 262,144 (both layers)
  u16* ipw16l1 = wbf + 524288;              // 262,144 (layer 1 only)

  prep<<<1728, 512, 0, stream>>>(x, in_w, in_b, ipw, opw, dtw, xpw,
                                 x16, opw16, ipw16l1, wc1, bias1, wc16);

  // ---------------- layer 0 (embed folded: K=32) ----------------
  {
    // xz = x @ Wc1^T + bias1  (M=8192,N=1024,K=32) -> bf16
    gemm_db<64, 128, 32, 1, 1><<<dim3(M_ROWS / 64, 8), 256, 0, stream>>>(
        x16, 32, wc1, 32, bias1, xz16, 1024, 1024, 32);

    conv_silu<<<dim3(8, 32), 512, 0, stream>>>(xz16, cw, cb, xc16);

    gemm_db<64, 128, 64, 2, 0><<<dim3(M_ROWS / 64, 5), 256, 0, stream>>>(
        xc16, 512, wc16, 512, dtb, xo, 544, 544, 512);

    scan_passA<<<dim3(8, 2, NCHUNK), 256, 0, stream>>>(
        xo, xc16, Alog, Ac, Bc);
    scan_mid<<<256, 256, 0, stream>>>(Ac, Bc, Hin);
    scan_passB<<<dim3(8, 2, NCHUNK), 256, 0, stream>>>(
        xo, xc16, xz16, Alog, Dsk, Hin, xc16);

    gemm_db<64, 64, 64, 0, 1><<<dim3(M_ROWS / 64, 4), 256, 0, stream>>>(
        xc16, 512, opw16, 512, nullptr, h16, 256, 256, 512);
  }

  // ---------------- layer 1 ----------------
  {
    const float* cw_l  = cw  + 512 * 4;
    const float* cb_l  = cb  + 512;
    const float* dtb_l = dtb + 512;
    const float* Al_l  = Alog + 512 * 16;
    const float* Dsk_l = Dsk + 512;
    const u16*   opw_l = opw16 + 256 * 512;
    const u16*   wc_l  = wc16 + 640 * 512;

    // xz = h @ ipw^T  (N=1024,K=256) -> bf16
    gemm_db<64, 128, 64, 0, 1><<<dim3(M_ROWS / 64, 8), 256, 0, stream>>>(
        h16, 256, ipw16l1, 256, nullptr, xz16, 1024, 1024, 256);

    conv_silu<<<dim3(8, 32), 512, 0, stream>>>(xz16, cw_l, cb_l, xc16);

    gemm_db<64, 128, 64, 2, 0><<<dim3(M_ROWS / 64, 5), 256, 0, stream>>>(
        xc16, 512, wc_l, 512, dtb_l, xo, 544, 544, 512);

    scan_passA<<<dim3(8, 2, NCHUNK), 256, 0, stream>>>(
        xo, xc16, Al_l, Ac, Bc);
    scan_mid<<<256, 256, 0, stream>>>(Ac, Bc, Hin);
    scan_passB<<<dim3(8, 2, NCHUNK), 256, 0, stream>>>(
        xo, xc16, xz16, Al_l, Dsk_l, Hin, xc16);

    gemm_db<64, 64, 64, 0, 1><<<dim3(M_ROWS / 64, 4), 256, 0, stream>>>(
        xc16, 512, opw_l, 512, nullptr, h16, 256, 256, 512);
  }

  head<<<8, 1024, 0, stream>>>(h16, p1w, p1b, p2w, p2b, (float*)d_out);
}

// Round 12
// 361.065 us; speedup vs baseline: 1.2951x; 1.0250x over previous
//
#include <hip/hip_runtime.h>
#include <math.h>

// ---------------------------------------------------------------------------
// Mamba forward. Round 12: R9 base (370us, passing) + single-kernel scan.
//  - COOPERATIVE LAUNCH ABANDONED: it crashes the harness's graph capture
//    (R10 silent-fail, R11 harness crash). Plain multi-kernel only.
//  - scanA+scanMid+scanB merged into ONE kernel: block=(b, 8-d group),
//    thread=(chunk c x d-lane); chunk prefix done in a 32KB LDS exchange.
//    Kills 4 launches/2 layers and all Ac/Bc/Hin HBM traffic (~40MB).
//  - kept from R9: BK=64 dbuf GEMMs w/ global_load_lds, embed folded into
//    L0 in_proj (K=32), merged prep, fused head.
// Shapes: B=8 L=1024 ENC=32 DM=256 DI=512 DS=16 DC=4 DTR=16 LAYERS=2 DFF=1024
// ---------------------------------------------------------------------------

static constexpr int L_SEQ = 1024;
static constexpr int M_ROWS = 8 * 1024;   // B*L
static constexpr int NCHUNK = 32;
static constexpr int TCHUNK = 32;         // L_SEQ / NCHUNK

typedef unsigned short u16;
typedef unsigned short u16x8 __attribute__((ext_vector_type(8)));
typedef unsigned short u16x4 __attribute__((ext_vector_type(4)));
typedef short bf16x8 __attribute__((ext_vector_type(8)));   // MFMA operand type
typedef float f32x4 __attribute__((ext_vector_type(4)));

__device__ __forceinline__ float silu_f(float x) { return x / (1.f + __expf(-x)); }
__device__ __forceinline__ float softplus_f(float x) {
  return (x > 20.f) ? x : log1pf(__expf(x));
}
__device__ __forceinline__ u16 f2bf(float f) {          // RNE fp32->bf16
  unsigned u = __builtin_bit_cast(unsigned, f);
  u += 0x7FFFu + ((u >> 16) & 1u);
  return (u16)(u >> 16);
}
__device__ __forceinline__ float bf2f(u16 v) {
  return __builtin_bit_cast(float, (unsigned)v << 16);
}

// async global->LDS, 16 B per lane; LDS dest = uniform base + lane*16
__device__ __forceinline__ void gll16(const u16* g, u16* l) {
  __builtin_amdgcn_global_load_lds(
      (const __attribute__((address_space(1))) void*)g,
      (__attribute__((address_space(3))) void*)l, 16, 0, 0);
}

// ---------------------------------------------------------------------------
// bf16 MFMA GEMM, double-buffered async staging, BK-wide K-step. (R9-proven)
// C[m,n] = epi( sum_k A[m,k]*W[n,k] ); A,W bf16 row-major (MxK / NxK).
// 256 thr = 4 waves (2x2), wave tile (BM/2)x(BN/2), MFMA 16x16x32.
// EPI: 0 none; 1 +bias; 2 combo (col<512 -> softplus(c+bias), else raw)
// OUTBF: 1 bf16 store, 0 fp32.  BM,BN mult of 64; K mult of BK;
// W must have >= gridDim.y*BN valid rows.
// ---------------------------------------------------------------------------
template<int BM,int BN,int BK,int EPI,int OUTBF>
__global__ __launch_bounds__(256)
void gemm_db(const u16* __restrict__ A, int lda,
             const u16* __restrict__ W, int ldw,
             const float* __restrict__ bias,
             void* __restrict__ Cp, int ldc,
             int N, int K)
{
  constexpr int KS = BK / 32;             // 16x16x32 sub-steps per K-iter
  constexpr int CA = BK / 8;              // 8-col chunks per 64-row group
  constexpr int NCH_A = (BM / 64) * CA;
  constexpr int NCH_B = (BN / 64) * CA;
  constexpr int TI = BM / 2 / 16;
  constexpr int TJ = BN / 2 / 16;

  __shared__ u16 As[2][BM * BK];
  __shared__ u16 Ws[2][BN * BK];

  const int tid = threadIdx.x;
  const int lane = tid & 63;
  const int wv = tid >> 6;
  const int wy = wv >> 1, wx = wv & 1;
  const int rb = wy * (BM / 2);
  const int cb = wx * (BN / 2);
  const int lr = lane & 15, lq = lane >> 4;
  const int bm = blockIdx.x * BM;
  const int bn = blockIdx.y * BN;

  f32x4 acc[TI][TJ];
#pragma unroll
  for (int i = 0; i < TI; ++i)
#pragma unroll
    for (int j = 0; j < TJ; ++j) acc[i][j] = (f32x4){0.f, 0.f, 0.f, 0.f};

  auto stage = [&](int k0, int buf) {
#pragma unroll
    for (int w = wv; w < NCH_A + NCH_B; w += 4) {
      if (w < NCH_A) {
        const int rh = w / CA, lqw = w % CA;
        gll16(A + (size_t)(bm + rh * 64 + lane) * lda + k0 + lqw * 8,
              &As[buf][(lqw * BM + rh * 64) * 8]);
      } else {
        const int w2 = w - NCH_A;
        const int rh = w2 / CA, lqw = w2 % CA;
        gll16(W + (size_t)(bn + rh * 64 + lane) * ldw + k0 + lqw * 8,
              &Ws[buf][(lqw * BN + rh * 64) * 8]);
      }
    }
  };

  stage(0, 0);
  int cur = 0;
  for (int k0 = 0; k0 < K; k0 += BK) {
    __syncthreads();                      // buf[cur] loads drained
    if (k0 + BK < K) stage(k0 + BK, cur ^ 1);

#pragma unroll
    for (int ks = 0; ks < KS; ++ks) {
      const int lqc = ks * 4 + lq;
      bf16x8 af[TI], bf[TJ];
#pragma unroll
      for (int i = 0; i < TI; ++i)
        af[i] = *reinterpret_cast<const bf16x8*>(
                  &As[cur][(lqc * BM + rb + i * 16 + lr) * 8]);
#pragma unroll
      for (int j = 0; j < TJ; ++j)
        bf[j] = *reinterpret_cast<const bf16x8*>(
                  &Ws[cur][(lqc * BN + cb + j * 16 + lr) * 8]);
#pragma unroll
      for (int i = 0; i < TI; ++i)
#pragma unroll
        for (int j = 0; j < TJ; ++j)
          acc[i][j] = __builtin_amdgcn_mfma_f32_16x16x32_bf16(af[i], bf[j], acc[i][j], 0, 0, 0);
    }
    cur ^= 1;
  }

#pragma unroll
  for (int i = 0; i < TI; ++i) {
#pragma unroll
    for (int j = 0; j < TJ; ++j) {
      const int col = bn + cb + j * 16 + lr;
      if (col >= N) continue;
#pragma unroll
      for (int r = 0; r < 4; ++r) {
        const int row = bm + rb + i * 16 + lq * 4 + r;
        float c = acc[i][j][r];
        if (EPI == 1) c += bias[col];
        if (EPI == 2) { if (col < 512) c = softplus_f(c + bias[col]); }
        if (OUTBF) ((u16*)Cp)[(size_t)row * ldc + col] = f2bf(c);
        else       ((float*)Cp)[(size_t)row * ldc + col] = c;
      }
    }
  }
}

// ---------------------------------------------------------------------------
// prep (1728 blocks x 512 thr): casts + folded weights (R9-proven).
// ---------------------------------------------------------------------------
__global__ __launch_bounds__(512)
void prep(const float* __restrict__ x, const float* __restrict__ in_w,
          const float* __restrict__ in_b,
          const float* __restrict__ ipw, const float* __restrict__ opw,
          const float* __restrict__ dtw, const float* __restrict__ xpw,
          u16* __restrict__ x16, u16* __restrict__ opw16,
          u16* __restrict__ ipw16l1, u16* __restrict__ wc1,
          float* __restrict__ bias1, u16* __restrict__ wc)
{
  const int blk = blockIdx.x;
  if (blk < 384) {
    const float* src; u16* dst; int base;
    if (blk < 128)      { src = x;            dst = x16;     base = blk; }
    else if (blk < 256) { src = opw;          dst = opw16;   base = blk - 128; }
    else                { src = ipw + 262144; dst = ipw16l1; base = blk - 256; }
    const int i = (base * 512 + threadIdx.x) * 4;
    float4 v = *reinterpret_cast<const float4*>(src + i);
    u16x4 o;
    o[0] = f2bf(v.x); o[1] = f2bf(v.y); o[2] = f2bf(v.z); o[3] = f2bf(v.w);
    *reinterpret_cast<u16x4*>(dst + i) = o;
  } else if (blk < 448) {
    const int t = threadIdx.x;
    const int n = (blk - 384) * 16 + (t >> 5);
    const int enc = t & 31;
    const float* iprow = ipw + (size_t)n * 256;       // layer 0
    float v = 0.f;
#pragma unroll 8
    for (int j = 0; j < 256; ++j) v = fmaf(iprow[j], in_w[j * 32 + enc], v);
    wc1[n * 32 + enc] = f2bf(v);
    if (enc == 0) {
      float bv = 0.f;
      for (int j = 0; j < 256; ++j) bv = fmaf(iprow[j], in_b[j], bv);
      bias1[n] = bv;
    }
  } else {
    const int idx = blk - 448;
    const int layer = idx / 640;
    const int n = idx % 640;
    const int k = threadIdx.x;
    const float* xp = xpw + (size_t)layer * 48 * 512;
    float v = 0.f;
    if (n < 512) {
      const float* dw = dtw + (size_t)layer * 512 * 16 + n * 16;
#pragma unroll
      for (int r = 0; r < 16; ++r) v = fmaf(dw[r], xp[r * 512 + k], v);
    } else if (n < 544) {
      v = xp[(16 + (n - 512)) * 512 + k];
    }
    wc[((size_t)layer * 640 + n) * 512 + k] = f2bf(v);
  }
}

// ---------------------------------------------------------------------------
// Causal depthwise conv (width 4) + bias + silu. xz bf16 (b,l,1024)[:,:512] -> xc bf16
// ---------------------------------------------------------------------------
__global__ __launch_bounds__(512)
void conv_silu(const u16* __restrict__ xz, const float* __restrict__ cw,
               const float* __restrict__ cb, u16* __restrict__ xc)
{
  const int b = blockIdx.x;          // 8
  const int l0 = blockIdx.y * 32;    // 32 chunks of 32
  const int d = threadIdx.x;         // 512

  const float w0 = cw[d * 4 + 0], w1 = cw[d * 4 + 1];
  const float w2 = cw[d * 4 + 2], w3 = cw[d * 4 + 3];
  const float bias = cb[d];

  const size_t base = ((size_t)b * L_SEQ) * 1024 + d;
  float xm3 = (l0 >= 3) ? bf2f(xz[base + (size_t)(l0 - 3) * 1024]) : 0.f;
  float xm2 = (l0 >= 2) ? bf2f(xz[base + (size_t)(l0 - 2) * 1024]) : 0.f;
  float xm1 = (l0 >= 1) ? bf2f(xz[base + (size_t)(l0 - 1) * 1024]) : 0.f;

#pragma unroll 4
  for (int i = 0; i < 32; ++i) {
    const int l = l0 + i;
    const float x0 = bf2f(xz[base + (size_t)l * 1024]);
    const float v = bias + w0 * xm3 + w1 * xm2 + w2 * xm1 + w3 * x0;
    xc[((size_t)b * L_SEQ + l) * 512 + d] = f2bf(silu_f(v));
    xm3 = xm2; xm2 = xm1; xm1 = x0;
  }
}

// ---------------------------------------------------------------------------
// Merged selective scan: ONE kernel. Block = (b, 8-d group) -> dim3(8,64),
// 256 threads = 32 chunks (tid>>3) x 8 d-lanes (tid&7).
//  pass A: each thread scans its 32-t chunk (h0=0), aggregates (p=prod dA,
//          h=local final) -> LDS exchange sAg/sBg [c][dl][n] (32 KB)
//  prefix: 128 threads serially combine the 32 chunk-aggregates per (dl,n);
//          exclusive prefix (Hin) overwrites sAg in place
//  pass B: seeded re-scan; writes yg = (y + u*D)*silu(z) bf16 in place of u
// B/C read from global (shared across the 64 d-blocks -> L2 broadcast);
// dt/u pass-B re-reads hit a 32KB/block L2-resident footprint.
// ---------------------------------------------------------------------------
__global__ __launch_bounds__(256)
void k_scan(const float* __restrict__ xo, const u16* __restrict__ u,
            const u16* __restrict__ xz, const float* __restrict__ Alog,
            const float* __restrict__ Dsk, u16* __restrict__ yg)
{
  const int b = blockIdx.x;
  const int d0 = blockIdx.y * 8;
  const int tid = threadIdx.x;
  const int dl = tid & 7;
  const int c = tid >> 3;
  const int d = d0 + dl;
  const int t0 = c * TCHUNK;

  __shared__ float sAg[NCHUNK][8][16];
  __shared__ float sBg[NCHUNK][8][16];

  float A[16], h[16], p[16];
  const float* al = Alog + d * 16;
#pragma unroll
  for (int n = 0; n < 16; ++n) { A[n] = -__expf(al[n]); h[n] = 0.f; p[n] = 1.f; }

  // ---- pass A: local chunk scan ----
#pragma unroll 2
  for (int t = 0; t < TCHUNK; ++t) {
    const size_t row = (size_t)b * L_SEQ + t0 + t;
    const float dtv = xo[row * 544 + d];
    const float uv  = bf2f(u[row * 512 + d]);
    const float cf  = dtv * uv;
    const f32x4* Bq = reinterpret_cast<const f32x4*>(&xo[row * 544 + 512]);
#pragma unroll
    for (int q = 0; q < 4; ++q) {
      const f32x4 Bv = Bq[q];
#pragma unroll
      for (int k = 0; k < 4; ++k) {
        const int n = q * 4 + k;
        const float dA = __expf(dtv * A[n]);
        p[n] *= dA;
        h[n] = fmaf(dA, h[n], cf * Bv[k]);
      }
    }
  }

#pragma unroll
  for (int q = 0; q < 4; ++q) {
    f32x4 va, vb;
#pragma unroll
    for (int k = 0; k < 4; ++k) { va[k] = p[q * 4 + k]; vb[k] = h[q * 4 + k]; }
    *reinterpret_cast<f32x4*>(&sAg[c][dl][q * 4]) = va;
    *reinterpret_cast<f32x4*>(&sBg[c][dl][q * 4]) = vb;
  }
  __syncthreads();

  // ---- chunk prefix in LDS: 128 chains of length 32 ----
  if (tid < 128) {
    const int pd = tid >> 4;         // 0..7
    const int pn = tid & 15;         // 0..15
    float hh = 0.f;
    for (int cc = 0; cc < NCHUNK; ++cc) {
      const float a  = sAg[cc][pd][pn];
      const float bb = sBg[cc][pd][pn];
      sAg[cc][pd][pn] = hh;          // exclusive prefix (Hin) in place
      hh = fmaf(a, hh, bb);
    }
  }
  __syncthreads();

  // ---- pass B: seeded scan + output ----
#pragma unroll
  for (int q = 0; q < 4; ++q) {
    const f32x4 v = *reinterpret_cast<const f32x4*>(&sAg[c][dl][q * 4]);
#pragma unroll
    for (int k = 0; k < 4; ++k) h[q * 4 + k] = v[k];
  }
  const float Dv = Dsk[d];

#pragma unroll 2
  for (int t = 0; t < TCHUNK; ++t) {
    const size_t row = (size_t)b * L_SEQ + t0 + t;
    const float dtv = xo[row * 544 + d];
    const float uv  = bf2f(u[row * 512 + d]);
    const float zf  = bf2f(xz[row * 1024 + 512 + d]);
    const float cf  = dtv * uv;
    const f32x4* Bq = reinterpret_cast<const f32x4*>(&xo[row * 544 + 512]);
    const f32x4* Cq = reinterpret_cast<const f32x4*>(&xo[row * 544 + 528]);
    float s0 = 0.f, s1 = 0.f, s2 = 0.f, s3 = 0.f;
#pragma unroll
    for (int q = 0; q < 4; ++q) {
      const f32x4 Bv = Bq[q];
      const f32x4 Cv = Cq[q];
#pragma unroll
      for (int k = 0; k < 4; ++k) {
        const int n = q * 4 + k;
        const float dA = __expf(dtv * A[n]);
        h[n] = fmaf(dA, h[n], cf * Bv[k]);
      }
      s0 = fmaf(h[q * 4 + 0], Cv[0], s0);
      s1 = fmaf(h[q * 4 + 1], Cv[1], s1);
      s2 = fmaf(h[q * 4 + 2], Cv[2], s2);
      s3 = fmaf(h[q * 4 + 3], Cv[3], s3);
    }
    const float yv = fmaf(uv, Dv, (s0 + s1) + (s2 + s3));
    yg[row * 512 + d] = f2bf(yv * silu_f(zf));
  }
}

// ---------------------------------------------------------------------------
// Fused head: one block per batch (R9-proven).
// ---------------------------------------------------------------------------
__global__ __launch_bounds__(1024)
void head(const u16* __restrict__ h, const float* __restrict__ p1w,
          const float* __restrict__ p1b, const float* __restrict__ p2w,
          const float* __restrict__ p2b, float* __restrict__ out)
{
  const int b = blockIdx.x;
  const int f = threadIdx.x;

  __shared__ float hl[256];
  if (f < 256) hl[f] = bf2f(h[((size_t)b * L_SEQ + (L_SEQ - 1)) * 256 + f]);
  __syncthreads();

  const float* wr = p1w + (size_t)f * 256;
  float acc = 0.f;
#pragma unroll 8
  for (int k = 0; k < 256; k += 4) {
    float4 wv = *reinterpret_cast<const float4*>(wr + k);
    acc = fmaf(hl[k + 0], wv.x, acc);
    acc = fmaf(hl[k + 1], wv.y, acc);
    acc = fmaf(hl[k + 2], wv.z, acc);
    acc = fmaf(hl[k + 3], wv.w, acc);
  }
  const float xv = acc + p1b[f];
  const float gg = 0.5f * xv * (1.f + erff(xv * 0.70710678118654752f));
  float s = gg * p2w[f];

  s += __shfl_xor(s, 1);
  s += __shfl_xor(s, 2);
  s += __shfl_xor(s, 4);
  s += __shfl_xor(s, 8);
  s += __shfl_xor(s, 16);
  s += __shfl_xor(s, 32);
  __shared__ float red[16];
  if ((f & 63) == 0) red[f >> 6] = s;
  __syncthreads();
  if (f == 0) {
    float t = 0.f;
#pragma unroll
    for (int i = 0; i < 16; ++i) t += red[i];
    out[b] = t + p2b[0];
  }
}

// ---------------------------------------------------------------------------
extern "C" void kernel_launch(void* const* d_in, const int* in_sizes, int n_in,
                              void* d_out, int out_size, void* d_ws, size_t ws_size,
                              hipStream_t stream)
{
  const float* x    = (const float*)d_in[0];
  const float* in_w = (const float*)d_in[1];
  const float* in_b = (const float*)d_in[2];
  const float* ipw  = (const float*)d_in[3];
  const float* cw   = (const float*)d_in[4];
  const float* cb   = (const float*)d_in[5];
  const float* xpw  = (const float*)d_in[6];
  const float* dtw  = (const float*)d_in[7];
  const float* dtb  = (const float*)d_in[8];
  const float* Alog = (const float*)d_in[9];
  const float* Dsk  = (const float*)d_in[10];
  const float* opw  = (const float*)d_in[11];
  const float* p1w  = (const float*)d_in[12];
  const float* p1b  = (const float*)d_in[13];
  const float* p2w  = (const float*)d_in[14];
  const float* p2b  = (const float*)d_in[15];

  float* ws = (float*)d_ws;
  // layout (fp32-word offsets)
  u16*   h16  = (u16*)(ws);                 // 8192*256  bf16 -> 1,048,576 fw
  u16*   xz16 = (u16*)(ws + 1048576);       // 8192*1024 bf16 -> 4,194,304 fw
  u16*   xc16 = (u16*)(ws + 5242880);       // 8192*512  bf16 -> 2,097,152 fw
  float* xo   = ws + 7340032;               // 8192*544  f32  -> 4,456,448 fw
  u16*   wc16 = (u16*)(ws + 11796480);      // 2*640*512 bf16 ->   327,680 fw
  u16*   wbf  = (u16*)(ws + 12124160);      // casts: 786432 u16 -> 393,216 fw
  u16*   wc1  = (u16*)(ws + 12517376);      // 1024*32 bf16 -> 16,384 fw
  float* bias1 = ws + 12533760;             // 1024 fw
  // end ~12.5M fw ~= 50.1 MB

  u16* x16     = wbf;                       // 262,144
  u16* opw16   = wbf + 262144;              // 262,144 (both layers)
  u16* ipw16l1 = wbf + 524288;              // 262,144 (layer 1 only)

  prep<<<1728, 512, 0, stream>>>(x, in_w, in_b, ipw, opw, dtw, xpw,
                                 x16, opw16, ipw16l1, wc1, bias1, wc16);

  // ---------------- layer 0 (embed folded: K=32) ----------------
  {
    // xz = x @ Wc1^T + bias1  (M=8192,N=1024,K=32) -> bf16
    gemm_db<64, 128, 32, 1, 1><<<dim3(M_ROWS / 64, 8), 256, 0, stream>>>(
        x16, 32, wc1, 32, bias1, xz16, 1024, 1024, 32);

    conv_silu<<<dim3(8, 32), 512, 0, stream>>>(xz16, cw, cb, xc16);

    gemm_db<64, 128, 64, 2, 0><<<dim3(M_ROWS / 64, 5), 256, 0, stream>>>(
        xc16, 512, wc16, 512, dtb, xo, 544, 544, 512);

    // merged scan (A + prefix + B), yg written in place of xc16
    k_scan<<<dim3(8, 64), 256, 0, stream>>>(xo, xc16, xz16, Alog, Dsk, xc16);

    gemm_db<64, 64, 64, 0, 1><<<dim3(M_ROWS / 64, 4), 256, 0, stream>>>(
        xc16, 512, opw16, 512, nullptr, h16, 256, 256, 512);
  }

  // ---------------- layer 1 ----------------
  {
    const float* cw_l  = cw  + 512 * 4;
    const float* cb_l  = cb  + 512;
    const float* dtb_l = dtb + 512;
    const float* Al_l  = Alog + 512 * 16;
    const float* Dsk_l = Dsk + 512;
    const u16*   opw_l = opw16 + 256 * 512;
    const u16*   wc_l  = wc16 + 640 * 512;

    // xz = h @ ipw^T  (N=1024,K=256) -> bf16
    gemm_db<64, 128, 64, 0, 1><<<dim3(M_ROWS / 64, 8), 256, 0, stream>>>(
        h16, 256, ipw16l1, 256, nullptr, xz16, 1024, 1024, 256);

    conv_silu<<<dim3(8, 32), 512, 0, stream>>>(xz16, cw_l, cb_l, xc16);

    gemm_db<64, 128, 64, 2, 0><<<dim3(M_ROWS / 64, 5), 256, 0, stream>>>(
        xc16, 512, wc_l, 512, dtb_l, xo, 544, 544, 512);

    k_scan<<<dim3(8, 64), 256, 0, stream>>>(xo, xc16, xz16, Al_l, Dsk_l, xc16);

    gemm_db<64, 64, 64, 0, 1><<<dim3(M_ROWS / 64, 4), 256, 0, stream>>>(
        xc16, 512, opw_l, 512, nullptr, h16, 256, 256, 512);
  }

  head<<<8, 1024, 0, stream>>>(h16, p1w, p1b, p2w, p2b, (float*)d_out);
}